// Round 2
// baseline (1500.083 us; speedup 1.0000x reference)
//
#include <hip/hip_runtime.h>
#include <hip/hip_bf16.h>

#define TOKENS 18
#define HDIM 1024
#define QLEN 9
#define IDIM 4096
#define NLAYER 8

// ws layout (floats)
#define QKV_OFF 18432            // h: [18][1024] at 0
#define QKV_STRIDE 23040         // per layer: [18][1280] (q 0..1023, k 1024..1151, v 1152..1279)
#define GU_OFF 202752            // 18432 + 8*23040
#define GU_STRIDE 147456         // per layer: [18][8192] (g 0..4095, u 4096..8191)
#define OUT_OFF 1382400          // 202752 + 8*147456 ; [2][4][64]
#define TOTAL_F 1382912

// ---------------- rstd over all 18 h-rows (block-wide, h is L2-resident) -------------
__device__ __forceinline__ void block_rstd18(const float* __restrict__ h,
                                             float* s_rstd, float* s_red) {
  int tid = threadIdx.x;
  float ss[TOKENS];
#pragma unroll
  for (int t = 0; t < TOKENS; t++) {
    float4 v = reinterpret_cast<const float4*>(h + (size_t)t * HDIM)[tid];
    ss[t] = v.x*v.x + v.y*v.y + v.z*v.z + v.w*v.w;
  }
#pragma unroll
  for (int off = 32; off >= 1; off >>= 1) {
#pragma unroll
    for (int t = 0; t < TOKENS; t++) ss[t] += __shfl_down(ss[t], off);
  }
  int wave = tid >> 6, lane = tid & 63;
  if (lane == 0) {
#pragma unroll
    for (int t = 0; t < TOKENS; t++) s_red[wave * TOKENS + t] = ss[t];
  }
  __syncthreads();
  if (tid < TOKENS) {
    float tot = s_red[tid] + s_red[TOKENS + tid] + s_red[2*TOKENS + tid] + s_red[3*TOKENS + tid];
    s_rstd[tid] = rsqrtf(tot * (1.0f / HDIM) + 1e-6f);
  }
  __syncthreads();
}

// ---------------- K0: build h (2,9,1024) --------------------------------------------
__global__ __launch_bounds__(256) void k_embed(
    const float* __restrict__ rnd, const float* __restrict__ dit,
    const float* __restrict__ feat, const float* __restrict__ t_all,
    const float* __restrict__ W_in, const float* __restrict__ b_in,
    const int* __restrict__ step, float* __restrict__ ws) {
  float* h = ws;
  int bid = blockIdx.x, tid = threadIdx.x;
  int st = step[0];
  const float* t = t_all + (size_t)st * HDIM;
  if (bid < 2) {                    // dh rows (q=0)
    int b = bid;
    for (int c = tid; c < HDIM; c += 256) {
      float v = t[c];
      if (b == 0) v += dit[c];
      h[(size_t)(b * QLEN) * HDIM + c] = v;
    }
  } else if (bid < 10) {            // feat_cond rows (q=1..4)
    int i = bid - 2;
    int b = i >> 2, p = i & 3;
    for (int c = tid; c < HDIM; c += 256)
      h[(size_t)(b * QLEN + 1 + p) * HDIM + c] = feat[(size_t)(b * 4 + p) * HDIM + c];
  } else {                          // x rows (q=5..8), same for both batches
    int p = bid - 10;
    __shared__ float rl[64];
    if (tid < 64) rl[tid] = rnd[p * 64 + tid];
    __syncthreads();
    for (int c = tid; c < HDIM; c += 256) {
      float acc = b_in[c];
#pragma unroll 8
      for (int f = 0; f < 64; f++) acc += rl[f] * W_in[(size_t)f * HDIM + c];
      h[(size_t)(5 + p) * HDIM + c] = acc;
      h[(size_t)(QLEN + 5 + p) * HDIM + c] = acc;
    }
  }
}

// ---------------- K1: qkv = rms(h)*ln1 @ [Wq|Wk|Wv] ---------------------------------
__global__ __launch_bounds__(256) void k_qkv(
    const float* __restrict__ Wq, const float* __restrict__ Wk,
    const float* __restrict__ Wv, const float* __restrict__ ln1,
    float* __restrict__ ws, int layer) {
  const float* h = ws;
  float* qkv = ws + QKV_OFF + (size_t)layer * QKV_STRIDE;
  __shared__ float s_rstd[TOKENS];
  __shared__ float s_red[4 * TOKENS];
  __shared__ float s_b[32][32];
  int tid = threadIdx.x;
  block_rstd18(h, s_rstd, s_red);
  int r0 = blockIdx.y * 32;
  const float* lw = ln1 + (size_t)layer * HDIM;
  for (int i = tid; i < 32 * TOKENS; i += 256) {
    int r = i / TOKENS, t = i - r * TOKENS;
    s_b[r][t] = h[(size_t)t * HDIM + r0 + r] * lw[r0 + r];
  }
  __syncthreads();
  int col = blockIdx.x * 256 + tid;
  const float* wp;
  int stride;
  if (col < 1024)      { wp = Wq + ((size_t)layer << 20) + col;                 stride = 1024; }
  else if (col < 1152) { wp = Wk + (size_t)layer * (1024 * 128) + (col - 1024); stride = 128;  }
  else                 { wp = Wv + (size_t)layer * (1024 * 128) + (col - 1152); stride = 128;  }
  wp += (size_t)r0 * stride;
  float acc[TOKENS];
#pragma unroll
  for (int t = 0; t < TOKENS; t++) acc[t] = 0.f;
#pragma unroll 4
  for (int r = 0; r < 32; r++) {
    float w = wp[(size_t)r * stride];
#pragma unroll
    for (int t = 0; t < TOKENS; t++) acc[t] += s_b[r][t] * w;
  }
#pragma unroll
  for (int t = 0; t < TOKENS; t++)
    atomicAdd(&qkv[(size_t)t * 1280 + col], acc[t] * s_rstd[t]);
}

// ---------------- K2: h += attn(qkv) @ Wo (attention recomputed per block) ----------
__global__ __launch_bounds__(256) void k_attn_o(
    const float* __restrict__ Wo, const float* __restrict__ cosq,
    const float* __restrict__ sinq, float* __restrict__ ws, int layer) {
  float* h = ws;
  const float* qkv = ws + QKV_OFF + (size_t)layer * QKV_STRIDE;
  __shared__ float lq[2][QLEN][68];
  __shared__ float lk[2][QLEN][68];
  __shared__ float lv[2][QLEN][36];
  __shared__ float sP[2][QLEN][12];
  __shared__ float sA[32][32];
  int tid = threadIdx.x;
  int r0 = blockIdx.y * 32;        // Wo row = head*64 + d
  int head = r0 >> 6;
  int kvh = head >> 3;             // GROUPS = 8
  int d0 = r0 & 63;                // 0 or 32
  // load q,k with RoPE (cos/sin already include DH^-0.25 scale)
  for (int i = tid; i < 2 * QLEN * 64; i += 256) {
    int d = i & 63;
    int qi = (i >> 6) % QLEN;
    int b = i / (QLEN * 64);
    const float* qr = qkv + (size_t)(b * QLEN + qi) * 1280;
    float c = cosq[qi * 64 + d], s = sinq[qi * 64 + d];
    float qv = qr[head * 64 + d];
    float qo = (d < 32) ? -qr[head * 64 + d + 32] : qr[head * 64 + d - 32];
    lq[b][qi][d] = qv * c + qo * s;
    float kv = qr[1024 + kvh * 64 + d];
    float ko = (d < 32) ? -qr[1024 + kvh * 64 + d + 32] : qr[1024 + kvh * 64 + d - 32];
    lk[b][qi][d] = kv * c + ko * s;
  }
  for (int i = tid; i < 2 * QLEN * 32; i += 256) {
    int d = i & 31;
    int ki = (i >> 5) % QLEN;
    int b = i / (QLEN * 32);
    lv[b][ki][d] = qkv[(size_t)(b * QLEN + ki) * 1280 + 1152 + kvh * 64 + d0 + d];
  }
  __syncthreads();
  for (int i = tid; i < 2 * QLEN * QLEN; i += 256) {
    int ki = i % QLEN;
    int qi = (i / QLEN) % QLEN;
    int b = i / (QLEN * QLEN);
    float s = 0.f;
#pragma unroll
    for (int d = 0; d < 64; d++) s += lq[b][qi][d] * lk[b][ki][d];
    sP[b][qi][ki] = s;
  }
  __syncthreads();
  if (tid < TOKENS) {
    int b = tid / QLEN, qi = tid % QLEN;
    float m = -1e30f;
#pragma unroll
    for (int k = 0; k < QLEN; k++) m = fmaxf(m, sP[b][qi][k]);
    float e[QLEN], sum = 0.f;
#pragma unroll
    for (int k = 0; k < QLEN; k++) { e[k] = expf(sP[b][qi][k] - m); sum += e[k]; }
    float inv = 1.f / sum;
#pragma unroll
    for (int k = 0; k < QLEN; k++) sP[b][qi][k] = e[k] * inv;
  }
  __syncthreads();
  for (int i = tid; i < 32 * TOKENS; i += 256) {
    int dd = i / TOKENS, t = i - dd * TOKENS;
    int b = t / QLEN, qi = t % QLEN;
    float a = 0.f;
#pragma unroll
    for (int k = 0; k < QLEN; k++) a += sP[b][qi][k] * lv[b][k][dd];
    sA[dd][t] = a;
  }
  __syncthreads();
  int col = blockIdx.x * 256 + tid;
  const float* wp = Wo + ((size_t)layer << 20) + (size_t)r0 * 1024 + col;
  float acc[TOKENS];
#pragma unroll
  for (int t = 0; t < TOKENS; t++) acc[t] = 0.f;
#pragma unroll 4
  for (int r = 0; r < 32; r++) {
    float w = wp[(size_t)r * 1024];
#pragma unroll
    for (int t = 0; t < TOKENS; t++) acc[t] += sA[r][t] * w;
  }
#pragma unroll
  for (int t = 0; t < TOKENS; t++)
    atomicAdd(&h[(size_t)t * HDIM + col], acc[t]);
}

// ---------------- K3: gu = rms(h)*ln2 @ [Wg|Wu] -------------------------------------
__global__ __launch_bounds__(256) void k_gu(
    const float* __restrict__ Wg, const float* __restrict__ Wu,
    const float* __restrict__ ln2, float* __restrict__ ws, int layer) {
  const float* h = ws;
  float* gu = ws + GU_OFF + (size_t)layer * GU_STRIDE;
  __shared__ float s_rstd[TOKENS];
  __shared__ float s_red[4 * TOKENS];
  __shared__ float s_b[32][32];
  int tid = threadIdx.x;
  block_rstd18(h, s_rstd, s_red);
  int r0 = blockIdx.y * 32;
  const float* lw = ln2 + (size_t)layer * HDIM;
  for (int i = tid; i < 32 * TOKENS; i += 256) {
    int r = i / TOKENS, t = i - r * TOKENS;
    s_b[r][t] = h[(size_t)t * HDIM + r0 + r] * lw[r0 + r];
  }
  __syncthreads();
  int cg = blockIdx.x;              // 0..3 -> Wg, 4..7 -> Wu
  const float* W;
  int outbase;
  if (cg < 4) { W = Wg + ((size_t)layer << 22); outbase = cg * 1024; }
  else        { W = Wu + ((size_t)layer << 22); outbase = 4096 + (cg - 4) * 1024; }
  int c = (outbase & 4095) + tid * 4;
  const float* wp = W + (size_t)r0 * IDIM + c;
  float4 acc[TOKENS];
#pragma unroll
  for (int t = 0; t < TOKENS; t++) acc[t] = make_float4(0.f, 0.f, 0.f, 0.f);
#pragma unroll 2
  for (int r = 0; r < 32; r++) {
    float4 w = *reinterpret_cast<const float4*>(wp + (size_t)r * IDIM);
#pragma unroll
    for (int t = 0; t < TOKENS; t++) {
      float bv = s_b[r][t];
      acc[t].x += bv * w.x; acc[t].y += bv * w.y;
      acc[t].z += bv * w.z; acc[t].w += bv * w.w;
    }
  }
  int ob = outbase + tid * 4;
#pragma unroll
  for (int t = 0; t < TOKENS; t++) {
    float rs = s_rstd[t];
    float* gp = gu + (size_t)t * 8192 + ob;
    atomicAdd(gp + 0, acc[t].x * rs);
    atomicAdd(gp + 1, acc[t].y * rs);
    atomicAdd(gp + 2, acc[t].z * rs);
    atomicAdd(gp + 3, acc[t].w * rs);
  }
}

// ---------------- K4: h += (silu(g)*u) @ Wd -----------------------------------------
__global__ __launch_bounds__(256) void k_wd(
    const float* __restrict__ Wd, float* __restrict__ ws, int layer) {
  float* h = ws;
  const float* gu = ws + GU_OFF + (size_t)layer * GU_STRIDE;
  __shared__ float s_b[32][32];
  int tid = threadIdx.x;
  int r0 = blockIdx.y * 32;         // r in [0,4096)
  for (int i = tid; i < 32 * TOKENS; i += 256) {
    int r = i / TOKENS, t = i - r * TOKENS;
    float g = gu[(size_t)t * 8192 + r0 + r];
    float u = gu[(size_t)t * 8192 + 4096 + r0 + r];
    s_b[r][t] = (g / (1.f + expf(-g))) * u;
  }
  __syncthreads();
  int c = tid * 4;
  const float* wp = Wd + ((size_t)layer << 22) + (size_t)r0 * 1024 + c;
  float4 acc[TOKENS];
#pragma unroll
  for (int t = 0; t < TOKENS; t++) acc[t] = make_float4(0.f, 0.f, 0.f, 0.f);
#pragma unroll 2
  for (int r = 0; r < 32; r++) {
    float4 w = *reinterpret_cast<const float4*>(wp + (size_t)r * 1024);
#pragma unroll
    for (int t = 0; t < TOKENS; t++) {
      float bv = s_b[r][t];
      acc[t].x += bv * w.x; acc[t].y += bv * w.y;
      acc[t].z += bv * w.z; acc[t].w += bv * w.w;
    }
  }
#pragma unroll
  for (int t = 0; t < TOKENS; t++) {
    float* hp = h + (size_t)t * HDIM + c;
    atomicAdd(hp + 0, acc[t].x);
    atomicAdd(hp + 1, acc[t].y);
    atomicAdd(hp + 2, acc[t].z);
    atomicAdd(hp + 3, acc[t].w);
  }
}

// ---------------- Kf1: outb = rms(h[:,5:])*norm_w @ W_out ---------------------------
__global__ __launch_bounds__(256) void k_out(
    const float* __restrict__ Wout, const float* __restrict__ normw,
    float* __restrict__ ws) {
  const float* h = ws;
  float* outb = ws + OUT_OFF;
  __shared__ float s_rstd[8];
  __shared__ float s_red[32];
  __shared__ float s_b[128][8];
  int tid = threadIdx.x;
  float ss[8];
#pragma unroll
  for (int s = 0; s < 8; s++) {
    int tix = (s >> 2) * QLEN + 5 + (s & 3);
    float4 v = reinterpret_cast<const float4*>(h + (size_t)tix * HDIM)[tid];
    ss[s] = v.x*v.x + v.y*v.y + v.z*v.z + v.w*v.w;
  }
#pragma unroll
  for (int off = 32; off >= 1; off >>= 1) {
#pragma unroll
    for (int s = 0; s < 8; s++) ss[s] += __shfl_down(ss[s], off);
  }
  int wave = tid >> 6, lane = tid & 63;
  if (lane == 0) {
#pragma unroll
    for (int s = 0; s < 8; s++) s_red[wave * 8 + s] = ss[s];
  }
  __syncthreads();
  if (tid < 8) {
    float tot = s_red[tid] + s_red[8 + tid] + s_red[16 + tid] + s_red[24 + tid];
    s_rstd[tid] = rsqrtf(tot * (1.f / HDIM) + 1e-6f);
  }
  __syncthreads();
  int r0 = blockIdx.x * 128;
  for (int i = tid; i < 128 * 8; i += 256) {
    int r = i >> 3, s = i & 7;
    int tix = (s >> 2) * QLEN + 5 + (s & 3);
    s_b[r][s] = h[(size_t)tix * HDIM + r0 + r] * normw[r0 + r] * s_rstd[s];
  }
  __syncthreads();
  int colc = tid & 63, rsub = tid >> 6;
  const float* wp = Wout + (size_t)(r0 + rsub * 32) * 64 + colc;
  float acc[8];
#pragma unroll
  for (int s = 0; s < 8; s++) acc[s] = 0.f;
#pragma unroll 4
  for (int r = 0; r < 32; r++) {
    float w = wp[(size_t)r * 64];
#pragma unroll
    for (int s = 0; s < 8; s++) acc[s] += s_b[rsub * 32 + r][s] * w;
  }
#pragma unroll
  for (int s = 0; s < 8; s++) atomicAdd(&outb[s * 64 + colc], acc[s]);
}

// ---------------- Kf2: cfg combine + write d_out (float32) --------------------------
__global__ __launch_bounds__(256) void k_final(
    const float* __restrict__ rnd, const float* __restrict__ cfg,
    const float* __restrict__ cfgm, const float* __restrict__ dt_all,
    const float* __restrict__ bout, const int* __restrict__ step,
    const float* __restrict__ ws, float* __restrict__ out) {
  const float* outb = ws + OUT_OFF;
  int tid = threadIdx.x;
  int f = tid & 63;
  float p = outb[tid] + bout[f];
  float n = outb[256 + tid] + bout[f];
  float pn = p * n, nn = n * n;
#pragma unroll
  for (int off = 32; off >= 1; off >>= 1) {
    pn += __shfl_down(pn, off);
    nn += __shfl_down(nn, off);
  }
  __shared__ float red[8];
  __shared__ float s_st;
  int wave = tid >> 6, lane = tid & 63;
  if (lane == 0) { red[wave] = pn; red[4 + wave] = nn; }
  __syncthreads();
  if (tid == 0) {
    float PN = red[0] + red[1] + red[2] + red[3];
    float NN = red[4] + red[5] + red[6] + red[7];
    s_st = PN / (NN + 1e-7f);
  }
  __syncthreads();
  int st = step[0];
  float dphi = cfgm[0] * n * s_st + cfg[0] * p;
  float next = rnd[tid] - dt_all[st] * dphi;
  if (tid == 0) out[0] = (float)(st + 1);
  out[1 + tid] = next;
}

// ---------------- launch ------------------------------------------------------------
extern "C" void kernel_launch(void* const* d_in, const int* in_sizes, int n_in,
                              void* d_out, int out_size, void* d_ws, size_t ws_size,
                              hipStream_t stream) {
  const float* rnd   = (const float*)d_in[0];
  const float* dit   = (const float*)d_in[1];
  const float* feat  = (const float*)d_in[2];
  const float* cfg   = (const float*)d_in[3];
  const float* cfgm  = (const float*)d_in[4];
  const float* t_all = (const float*)d_in[5];
  const float* dt_al = (const float*)d_in[6];
  const float* cosq  = (const float*)d_in[7];
  const float* sinq  = (const float*)d_in[8];
  const float* W_in  = (const float*)d_in[9];
  const float* b_in  = (const float*)d_in[10];
  const float* ln1   = (const float*)d_in[11];
  const float* Wq    = (const float*)d_in[12];
  const float* Wk    = (const float*)d_in[13];
  const float* Wv    = (const float*)d_in[14];
  const float* Wo    = (const float*)d_in[15];
  const float* ln2   = (const float*)d_in[16];
  const float* Wg    = (const float*)d_in[17];
  const float* Wu    = (const float*)d_in[18];
  const float* Wd    = (const float*)d_in[19];
  const float* normw = (const float*)d_in[20];
  const float* Wout  = (const float*)d_in[21];
  const float* bout  = (const float*)d_in[22];
  const int*   step  = (const int*)d_in[23];
  float* ws = (float*)d_ws;

  // zero all atomic-accumulation regions (qkv, gu, outb)
  hipMemsetAsync((void*)(ws + QKV_OFF), 0, (size_t)(TOTAL_F - QKV_OFF) * sizeof(float), stream);

  k_embed<<<14, 256, 0, stream>>>(rnd, dit, feat, t_all, W_in, b_in, step, ws);
  for (int l = 0; l < NLAYER; l++) {
    k_qkv<<<dim3(5, 32), 256, 0, stream>>>(Wq, Wk, Wv, ln1, ws, l);
    k_attn_o<<<dim3(4, 32), 256, 0, stream>>>(Wo, cosq, sinq, ws, l);
    k_gu<<<dim3(8, 32), 256, 0, stream>>>(Wg, Wu, ln2, ws, l);
    k_wd<<<dim3(1, 128), 256, 0, stream>>>(Wd, ws, l);
  }
  k_out<<<8, 256, 0, stream>>>(Wout, normw, ws);
  k_final<<<1, 256, 0, stream>>>(rnd, cfg, cfgm, dt_al, bout, step, ws, (float*)d_out);
}

// Round 3
// 747.204 us; speedup vs baseline: 2.0076x; 2.0076x over previous
//
#include <hip/hip_runtime.h>
#include <hip/hip_bf16.h>

#define TOKENS 18
#define HDIM 1024
#define QLEN 9
#define IDIM 4096
#define NLAYER 8

// ws layout (float offsets)
#define H_OFF     0               // h: [18][1024]
#define QKV_OFF   18432           // reduced qkv: [18][1280]
#define QKVP_OFF  41472           // qkv partials: [32][18][1280]
#define OP_OFF    778752          // attn-out partials: [32][18][1024]
#define GUP_OFF   1368576         // gu partials: [32][18][8192]
#define WDP_OFF   6087168         // wd partials: [128][18][1024]
#define OUTP_OFF  8446464         // out partials: [32][512]
#define TOTAL_F   8462848         // ~33.9 MB

// ---------------- rstd over all 18 h-rows (block-wide, h is L2-resident) -------------
__device__ __forceinline__ void block_rstd18(const float* __restrict__ h,
                                             float* s_rstd, float* s_red) {
  int tid = threadIdx.x;
  float ss[TOKENS];
#pragma unroll
  for (int t = 0; t < TOKENS; t++) {
    float4 v = reinterpret_cast<const float4*>(h + (size_t)t * HDIM)[tid];
    ss[t] = v.x*v.x + v.y*v.y + v.z*v.z + v.w*v.w;
  }
#pragma unroll
  for (int off = 32; off >= 1; off >>= 1) {
#pragma unroll
    for (int t = 0; t < TOKENS; t++) ss[t] += __shfl_down(ss[t], off);
  }
  int wave = tid >> 6, lane = tid & 63;
  if (lane == 0) {
#pragma unroll
    for (int t = 0; t < TOKENS; t++) s_red[wave * TOKENS + t] = ss[t];
  }
  __syncthreads();
  if (tid < TOKENS) {
    float tot = s_red[tid] + s_red[TOKENS + tid] + s_red[2*TOKENS + tid] + s_red[3*TOKENS + tid];
    s_rstd[tid] = rsqrtf(tot * (1.0f / HDIM) + 1e-6f);
  }
  __syncthreads();
}

// ---------------- generic partial reducer: dst[i] (+)= sum_p src[p*n+i] -------------
__global__ __launch_bounds__(256) void k_red(
    const float* __restrict__ src, float* __restrict__ dst,
    int nparts, int n, int accum) {
  int idx = blockIdx.x * 256 + threadIdx.x;
  if (idx >= n) return;
  float s = 0.f;
#pragma unroll 8
  for (int p = 0; p < nparts; p++) s += src[(size_t)p * n + idx];
  dst[idx] = accum ? (dst[idx] + s) : s;
}

// ---------------- K0: build h (2,9,1024) --------------------------------------------
__global__ __launch_bounds__(256) void k_embed(
    const float* __restrict__ rnd, const float* __restrict__ dit,
    const float* __restrict__ feat, const float* __restrict__ t_all,
    const float* __restrict__ W_in, const float* __restrict__ b_in,
    const int* __restrict__ step, float* __restrict__ ws) {
  float* h = ws;
  int bid = blockIdx.x, tid = threadIdx.x;
  int st = step[0];
  const float* t = t_all + (size_t)st * HDIM;
  if (bid < 2) {                    // dh rows (q=0)
    int b = bid;
    for (int c = tid; c < HDIM; c += 256) {
      float v = t[c];
      if (b == 0) v += dit[c];
      h[(size_t)(b * QLEN) * HDIM + c] = v;
    }
  } else if (bid < 10) {            // feat_cond rows (q=1..4)
    int i = bid - 2;
    int b = i >> 2, p = i & 3;
    for (int c = tid; c < HDIM; c += 256)
      h[(size_t)(b * QLEN + 1 + p) * HDIM + c] = feat[(size_t)(b * 4 + p) * HDIM + c];
  } else {                          // x rows (q=5..8), same for both batches
    int p = bid - 10;
    __shared__ float rl[64];
    if (tid < 64) rl[tid] = rnd[p * 64 + tid];
    __syncthreads();
    for (int c = tid; c < HDIM; c += 256) {
      float acc = b_in[c];
#pragma unroll 8
      for (int f = 0; f < 64; f++) acc += rl[f] * W_in[(size_t)f * HDIM + c];
      h[(size_t)(5 + p) * HDIM + c] = acc;
      h[(size_t)(QLEN + 5 + p) * HDIM + c] = acc;
    }
  }
}

// ---------------- K1: qkv_part[by] = rms(h)*ln1 @ [Wq|Wk|Wv] (rows r0..r0+31) -------
__global__ __launch_bounds__(256) void k_qkv(
    const float* __restrict__ Wq, const float* __restrict__ Wk,
    const float* __restrict__ Wv, const float* __restrict__ ln1,
    float* __restrict__ ws, int layer) {
  const float* h = ws;
  float* qp = ws + QKVP_OFF + (size_t)blockIdx.y * (TOKENS * 1280);
  __shared__ float s_rstd[TOKENS];
  __shared__ float s_red[4 * TOKENS];
  __shared__ float s_b[32][32];
  int tid = threadIdx.x;
  block_rstd18(h, s_rstd, s_red);
  int r0 = blockIdx.y * 32;
  const float* lw = ln1 + (size_t)layer * HDIM;
  for (int i = tid; i < 32 * TOKENS; i += 256) {
    int r = i / TOKENS, t = i - r * TOKENS;
    s_b[r][t] = h[(size_t)t * HDIM + r0 + r] * lw[r0 + r];
  }
  __syncthreads();
  int col = blockIdx.x * 256 + tid;
  const float* wp;
  int stride;
  if (col < 1024)      { wp = Wq + ((size_t)layer << 20) + col;                 stride = 1024; }
  else if (col < 1152) { wp = Wk + (size_t)layer * (1024 * 128) + (col - 1024); stride = 128;  }
  else                 { wp = Wv + (size_t)layer * (1024 * 128) + (col - 1152); stride = 128;  }
  wp += (size_t)r0 * stride;
  float acc[TOKENS];
#pragma unroll
  for (int t = 0; t < TOKENS; t++) acc[t] = 0.f;
#pragma unroll 8
  for (int r = 0; r < 32; r++) {
    float w = wp[(size_t)r * stride];
#pragma unroll
    for (int t = 0; t < TOKENS; t++) acc[t] += s_b[r][t] * w;
  }
#pragma unroll
  for (int t = 0; t < TOKENS; t++)
    qp[(size_t)t * 1280 + col] = acc[t] * s_rstd[t];
}

// ---------------- K2: o_part[by] = attn(qkv) @ Wo(rows r0..r0+31) ------------------
__global__ __launch_bounds__(256) void k_attn_o(
    const float* __restrict__ Wo, const float* __restrict__ cosq,
    const float* __restrict__ sinq, float* __restrict__ ws, int layer) {
  const float* qkv = ws + QKV_OFF;
  float* op = ws + OP_OFF + (size_t)blockIdx.y * (TOKENS * HDIM);
  __shared__ float lq[2][QLEN][68];
  __shared__ float lk[2][QLEN][68];
  __shared__ float lv[2][QLEN][36];
  __shared__ float sP[2][QLEN][12];
  __shared__ float sA[32][32];
  int tid = threadIdx.x;
  int r0 = blockIdx.y * 32;        // Wo row = head*64 + d
  int head = r0 >> 6;
  int kvh = head >> 3;             // GROUPS = 8
  int d0 = r0 & 63;                // 0 or 32
  for (int i = tid; i < 2 * QLEN * 64; i += 256) {
    int d = i & 63;
    int qi = (i >> 6) % QLEN;
    int b = i / (QLEN * 64);
    const float* qr = qkv + (size_t)(b * QLEN + qi) * 1280;
    float c = cosq[qi * 64 + d], s = sinq[qi * 64 + d];
    float qv = qr[head * 64 + d];
    float qo = (d < 32) ? -qr[head * 64 + d + 32] : qr[head * 64 + d - 32];
    lq[b][qi][d] = qv * c + qo * s;
    float kv = qr[1024 + kvh * 64 + d];
    float ko = (d < 32) ? -qr[1024 + kvh * 64 + d + 32] : qr[1024 + kvh * 64 + d - 32];
    lk[b][qi][d] = kv * c + ko * s;
  }
  for (int i = tid; i < 2 * QLEN * 32; i += 256) {
    int d = i & 31;
    int ki = (i >> 5) % QLEN;
    int b = i / (QLEN * 32);
    lv[b][ki][d] = qkv[(size_t)(b * QLEN + ki) * 1280 + 1152 + kvh * 64 + d0 + d];
  }
  __syncthreads();
  for (int i = tid; i < 2 * QLEN * QLEN; i += 256) {
    int ki = i % QLEN;
    int qi = (i / QLEN) % QLEN;
    int b = i / (QLEN * QLEN);
    float s = 0.f;
#pragma unroll
    for (int d = 0; d < 64; d++) s += lq[b][qi][d] * lk[b][ki][d];
    sP[b][qi][ki] = s;
  }
  __syncthreads();
  if (tid < TOKENS) {
    int b = tid / QLEN, qi = tid % QLEN;
    float m = -1e30f;
#pragma unroll
    for (int k = 0; k < QLEN; k++) m = fmaxf(m, sP[b][qi][k]);
    float e[QLEN], sum = 0.f;
#pragma unroll
    for (int k = 0; k < QLEN; k++) { e[k] = expf(sP[b][qi][k] - m); sum += e[k]; }
    float inv = 1.f / sum;
#pragma unroll
    for (int k = 0; k < QLEN; k++) sP[b][qi][k] = e[k] * inv;
  }
  __syncthreads();
  for (int i = tid; i < 32 * TOKENS; i += 256) {
    int dd = i / TOKENS, t = i - dd * TOKENS;
    int b = t / QLEN, qi = t % QLEN;
    float a = 0.f;
#pragma unroll
    for (int k = 0; k < QLEN; k++) a += sP[b][qi][k] * lv[b][k][dd];
    sA[dd][t] = a;
  }
  __syncthreads();
  int col = blockIdx.x * 256 + tid;
  const float* wp = Wo + ((size_t)layer << 20) + (size_t)r0 * 1024 + col;
  float acc[TOKENS];
#pragma unroll
  for (int t = 0; t < TOKENS; t++) acc[t] = 0.f;
#pragma unroll 8
  for (int r = 0; r < 32; r++) {
    float w = wp[(size_t)r * 1024];
#pragma unroll
    for (int t = 0; t < TOKENS; t++) acc[t] += sA[r][t] * w;
  }
#pragma unroll
  for (int t = 0; t < TOKENS; t++)
    op[(size_t)t * HDIM + col] = acc[t];
}

// ---------------- K3: gu_part[by] = rms(h)*ln2 @ [Wg|Wu] (rows r0..r0+31) -----------
__global__ __launch_bounds__(256) void k_gu(
    const float* __restrict__ Wg, const float* __restrict__ Wu,
    const float* __restrict__ ln2, float* __restrict__ ws, int layer) {
  const float* h = ws;
  float* gup = ws + GUP_OFF + (size_t)blockIdx.y * (TOKENS * 8192);
  __shared__ float s_rstd[TOKENS];
  __shared__ float s_red[4 * TOKENS];
  __shared__ float s_b[32][32];
  int tid = threadIdx.x;
  block_rstd18(h, s_rstd, s_red);
  int r0 = blockIdx.y * 32;
  const float* lw = ln2 + (size_t)layer * HDIM;
  for (int i = tid; i < 32 * TOKENS; i += 256) {
    int r = i / TOKENS, t = i - r * TOKENS;
    s_b[r][t] = h[(size_t)t * HDIM + r0 + r] * lw[r0 + r];
  }
  __syncthreads();
  int cg = blockIdx.x;              // 0..3 -> Wg, 4..7 -> Wu
  const float* W;
  int outbase;
  if (cg < 4) { W = Wg + ((size_t)layer << 22); outbase = cg * 1024; }
  else        { W = Wu + ((size_t)layer << 22); outbase = 4096 + (cg - 4) * 1024; }
  int c = (outbase & 4095) + tid * 4;
  const float* wp = W + (size_t)r0 * IDIM + c;
  float4 acc[TOKENS];
#pragma unroll
  for (int t = 0; t < TOKENS; t++) acc[t] = make_float4(0.f, 0.f, 0.f, 0.f);
#pragma unroll 8
  for (int r = 0; r < 32; r++) {
    float4 w = *reinterpret_cast<const float4*>(wp + (size_t)r * IDIM);
#pragma unroll
    for (int t = 0; t < TOKENS; t++) {
      float bv = s_b[r][t];
      acc[t].x += bv * w.x; acc[t].y += bv * w.y;
      acc[t].z += bv * w.z; acc[t].w += bv * w.w;
    }
  }
  int ob = outbase + tid * 4;
#pragma unroll
  for (int t = 0; t < TOKENS; t++) {
    float rs = s_rstd[t];
    float4 o = make_float4(acc[t].x * rs, acc[t].y * rs, acc[t].z * rs, acc[t].w * rs);
    *reinterpret_cast<float4*>(gup + (size_t)t * 8192 + ob) = o;
  }
}

// ---------------- K4: wd_part[by] = (silu(g)*u)(rows r0..r0+31) @ Wd ----------------
// gu reduction over 32 partials fused into the prologue.
__global__ __launch_bounds__(256) void k_wd(
    const float* __restrict__ Wd, float* __restrict__ ws, int layer) {
  const float* gup = ws + GUP_OFF;
  float* wdp = ws + WDP_OFF + (size_t)blockIdx.y * (TOKENS * HDIM);
  __shared__ float s_b[32][32];   // [r][t]
  int tid = threadIdx.x;
  int r0 = blockIdx.y * 32;       // r in [0,4096)
  for (int i = tid; i < 32 * TOKENS; i += 256) {
    int t = i >> 5, r = i & 31;
    const float* base = gup + (size_t)t * 8192 + r0 + r;
    float g = 0.f, u = 0.f;
#pragma unroll 8
    for (int p = 0; p < 32; p++) {
      g += base[(size_t)p * (TOKENS * 8192)];
      u += base[(size_t)p * (TOKENS * 8192) + 4096];
    }
    s_b[r][t] = (g / (1.f + expf(-g))) * u;
  }
  __syncthreads();
  int c = tid * 4;
  const float* wp = Wd + ((size_t)layer << 22) + (size_t)r0 * 1024 + c;
  float4 acc[TOKENS];
#pragma unroll
  for (int t = 0; t < TOKENS; t++) acc[t] = make_float4(0.f, 0.f, 0.f, 0.f);
#pragma unroll 8
  for (int r = 0; r < 32; r++) {
    float4 w = *reinterpret_cast<const float4*>(wp + (size_t)r * 1024);
#pragma unroll
    for (int t = 0; t < TOKENS; t++) {
      float bv = s_b[r][t];
      acc[t].x += bv * w.x; acc[t].y += bv * w.y;
      acc[t].z += bv * w.z; acc[t].w += bv * w.w;
    }
  }
#pragma unroll
  for (int t = 0; t < TOKENS; t++)
    *reinterpret_cast<float4*>(wdp + (size_t)t * HDIM + c) = acc[t];
}

// ---------------- Kf1: outb_part = rms(h[:,5:])*norm_w @ W_out ----------------------
__global__ __launch_bounds__(256) void k_out(
    const float* __restrict__ Wout, const float* __restrict__ normw,
    float* __restrict__ ws) {
  const float* h = ws;
  float* outp = ws + OUTP_OFF;
  __shared__ float s_rstd[8];
  __shared__ float s_red[32];
  __shared__ float s_b[128][8];
  int tid = threadIdx.x;
  float ss[8];
#pragma unroll
  for (int s = 0; s < 8; s++) {
    int tix = (s >> 2) * QLEN + 5 + (s & 3);
    float4 v = reinterpret_cast<const float4*>(h + (size_t)tix * HDIM)[tid];
    ss[s] = v.x*v.x + v.y*v.y + v.z*v.z + v.w*v.w;
  }
#pragma unroll
  for (int off = 32; off >= 1; off >>= 1) {
#pragma unroll
    for (int s = 0; s < 8; s++) ss[s] += __shfl_down(ss[s], off);
  }
  int wave = tid >> 6, lane = tid & 63;
  if (lane == 0) {
#pragma unroll
    for (int s = 0; s < 8; s++) s_red[wave * 8 + s] = ss[s];
  }
  __syncthreads();
  if (tid < 8) {
    float tot = s_red[tid] + s_red[8 + tid] + s_red[16 + tid] + s_red[24 + tid];
    s_rstd[tid] = rsqrtf(tot * (1.f / HDIM) + 1e-6f);
  }
  __syncthreads();
  int r0 = blockIdx.x * 128;
  for (int i = tid; i < 128 * 8; i += 256) {
    int r = i >> 3, s = i & 7;
    int tix = (s >> 2) * QLEN + 5 + (s & 3);
    s_b[r][s] = h[(size_t)tix * HDIM + r0 + r] * normw[r0 + r] * s_rstd[s];
  }
  __syncthreads();
  int colc = tid & 63, rsub = tid >> 6;
  const float* wp = Wout + (size_t)(r0 + rsub * 32) * 64 + colc;
  float acc[8];
#pragma unroll
  for (int s = 0; s < 8; s++) acc[s] = 0.f;
#pragma unroll 8
  for (int r = 0; r < 32; r++) {
    float w = wp[(size_t)r * 64];
#pragma unroll
    for (int s = 0; s < 8; s++) acc[s] += s_b[rsub * 32 + r][s] * w;
  }
  // partial slot per (block, rsub): 32 partials of [8][64]
  float* slot = outp + (size_t)(blockIdx.x * 4 + rsub) * 512;
#pragma unroll
  for (int s = 0; s < 8; s++) slot[s * 64 + colc] = acc[s];
}

// ---------------- Kf2: cfg combine + write d_out (float32) --------------------------
__global__ __launch_bounds__(256) void k_final(
    const float* __restrict__ rnd, const float* __restrict__ cfg,
    const float* __restrict__ cfgm, const float* __restrict__ dt_all,
    const float* __restrict__ bout, const int* __restrict__ step,
    const float* __restrict__ ws, float* __restrict__ out) {
  const float* outp = ws + OUTP_OFF;
  int tid = threadIdx.x;
  int f = tid & 63;
  float p = bout[f], n = bout[f];
#pragma unroll 8
  for (int pp = 0; pp < 32; pp++) {
    p += outp[(size_t)pp * 512 + tid];
    n += outp[(size_t)pp * 512 + 256 + tid];
  }
  float pn = p * n, nn = n * n;
#pragma unroll
  for (int off = 32; off >= 1; off >>= 1) {
    pn += __shfl_down(pn, off);
    nn += __shfl_down(nn, off);
  }
  __shared__ float red[8];
  __shared__ float s_st;
  int wave = tid >> 6, lane = tid & 63;
  if (lane == 0) { red[wave] = pn; red[4 + wave] = nn; }
  __syncthreads();
  if (tid == 0) {
    float PN = red[0] + red[1] + red[2] + red[3];
    float NN = red[4] + red[5] + red[6] + red[7];
    s_st = PN / (NN + 1e-7f);
  }
  __syncthreads();
  int st = step[0];
  float dphi = cfgm[0] * n * s_st + cfg[0] * p;
  float next = rnd[tid] - dt_all[st] * dphi;
  if (tid == 0) out[0] = (float)(st + 1);
  out[1 + tid] = next;
}

// ---------------- launch ------------------------------------------------------------
extern "C" void kernel_launch(void* const* d_in, const int* in_sizes, int n_in,
                              void* d_out, int out_size, void* d_ws, size_t ws_size,
                              hipStream_t stream) {
  const float* rnd   = (const float*)d_in[0];
  const float* dit   = (const float*)d_in[1];
  const float* feat  = (const float*)d_in[2];
  const float* cfg   = (const float*)d_in[3];
  const float* cfgm  = (const float*)d_in[4];
  const float* t_all = (const float*)d_in[5];
  const float* dt_al = (const float*)d_in[6];
  const float* cosq  = (const float*)d_in[7];
  const float* sinq  = (const float*)d_in[8];
  const float* W_in  = (const float*)d_in[9];
  const float* b_in  = (const float*)d_in[10];
  const float* ln1   = (const float*)d_in[11];
  const float* Wq    = (const float*)d_in[12];
  const float* Wk    = (const float*)d_in[13];
  const float* Wv    = (const float*)d_in[14];
  const float* Wo    = (const float*)d_in[15];
  const float* ln2   = (const float*)d_in[16];
  const float* Wg    = (const float*)d_in[17];
  const float* Wu    = (const float*)d_in[18];
  const float* Wd    = (const float*)d_in[19];
  const float* normw = (const float*)d_in[20];
  const float* Wout  = (const float*)d_in[21];
  const float* bout  = (const float*)d_in[22];
  const int*   step  = (const int*)d_in[23];
  float* ws = (float*)d_ws;

  k_embed<<<14, 256, 0, stream>>>(rnd, dit, feat, t_all, W_in, b_in, step, ws);
  for (int l = 0; l < NLAYER; l++) {
    k_qkv<<<dim3(5, 32), 256, 0, stream>>>(Wq, Wk, Wv, ln1, ws, l);
    k_red<<<90, 256, 0, stream>>>(ws + QKVP_OFF, ws + QKV_OFF, 32, TOKENS * 1280, 0);
    k_attn_o<<<dim3(4, 32), 256, 0, stream>>>(Wo, cosq, sinq, ws, l);
    k_red<<<72, 256, 0, stream>>>(ws + OP_OFF, ws + H_OFF, 32, TOKENS * HDIM, 1);
    k_gu<<<dim3(8, 32), 256, 0, stream>>>(Wg, Wu, ln2, ws, l);
    k_wd<<<dim3(1, 128), 256, 0, stream>>>(Wd, ws, l);
    k_red<<<72, 256, 0, stream>>>(ws + WDP_OFF, ws + H_OFF, 128, TOKENS * HDIM, 1);
  }
  k_out<<<8, 256, 0, stream>>>(Wout, normw, ws);
  k_final<<<1, 256, 0, stream>>>(rnd, cfg, cfgm, dt_al, bout, step, ws, (float*)d_out);
}